// Round 12
// baseline (1220.942 us; speedup 1.0000x reference)
//
#include <hip/hip_runtime.h>
#include <stdint.h>

typedef __attribute__((ext_vector_type(8))) short short8;
typedef __attribute__((ext_vector_type(4))) float f32x4;

#define DEVI __device__ __forceinline__

// float -> bf16 bits, round-to-nearest-even
DEVI unsigned short f2b(float f) {
  union { float f; unsigned u; } v; v.f = f;
  return (unsigned short)((v.u + 0x7fffu + ((v.u >> 16) & 1u)) >> 16);
}

// async global->LDS, 16B per lane; LDS dest must be wave-uniform base + lane*16
#define GLD16(g, s) __builtin_amdgcn_global_load_lds( \
    (const __attribute__((address_space(1))) void*)(g), \
    (__attribute__((address_space(3))) void*)(s), 16, 0, 0)

#define NBLOCKS 1024u

// Grid barrier: one dedicated counter per call site (zeroed by hipMemsetAsync
// before launch). Device-scope atomics + agent-scope fences (cross-XCD safe,
// G16/m20). Requires all NBLOCKS co-resident: grid==256CU*4blk/CU exact,
// LDS 32KB (<=5/CU), launch_bounds(256,4) caps VGPR<=128.
DEVI void gbar(unsigned* cnt) {
  __syncthreads();
  if (threadIdx.x == 0) {
    __threadfence();  // release: phase writes visible device-wide
    atomicAdd(cnt, 1u);
    while (atomicAdd(cnt, 0u) < NBLOCKS) __builtin_amdgcn_s_sleep(8);
    __threadfence();  // acquire: see other blocks' writes
  }
  __syncthreads();
}

// ---------------------------------------------------------------------------
// NT GEMM tile body: identical to R10 (2-buffer ring, vmcnt(0), swizzle).
// EPI: 0 = store bf16; 1 = store f32 * scale; 2 = store f32 + resid
template <int EPI>
DEVI void gemm_body(const unsigned short* __restrict__ A,
                    const unsigned short* __restrict__ B, void* __restrict__ Cv,
                    const float* __restrict__ resid, int bm, int bn, int K, int lda,
                    int ldb, int ldc, float scale, unsigned short* lds) {
  const int tid = threadIdx.x;
  const int wave = tid >> 6, lane = tid & 63;
  const int wm = wave >> 1, wn = wave & 1;

  f32x4 acc[4][4] = {};

  const int r0 = wave * 32 + (lane >> 2);
  const int c0 = (((lane & 3) ^ ((lane >> 3) & 3)) * 8);  // swizzled source slot
  const unsigned short* ga = A + (size_t)(bm * 128 + r0) * lda + c0;
  const unsigned short* gb = B + (size_t)(bn * 128 + r0) * ldb + c0;
  const size_t stepA16 = (size_t)16 * lda;
  const size_t stepB16 = (size_t)16 * ldb;
  unsigned short* sbase = lds + wave * 1024 + lane * 8;

  const int rowa = wm * 64 + (lane & 15);
  const int rowb = wn * 64 + (lane & 15);
  const int kch = (((lane >> 4) ^ ((lane >> 1) & 3)) * 8);  // swizzled read slot

  const int nK = K >> 5;

  auto stage = [&](int kt, int buf) {
    const unsigned short* gA = ga + kt * 32;
    const unsigned short* gB = gb + kt * 32;
    unsigned short* dA = sbase + buf * 8192;
    unsigned short* dB = dA + 4096;
    GLD16(gA, dA);
    GLD16(gA + stepA16, dA + 512);
    GLD16(gB, dB);
    GLD16(gB + stepB16, dB + 512);
  };

  stage(0, 0);
  for (int kt = 0; kt < nK; ++kt) {
    asm volatile("s_waitcnt vmcnt(0)" ::: "memory");  // stage(kt) resident
    __builtin_amdgcn_s_barrier();
    asm volatile("" ::: "memory");
    if (kt + 1 < nK) stage(kt + 1, (kt + 1) & 1);
    const unsigned short* Ab = lds + (kt & 1) * 8192;
    const unsigned short* Bb = Ab + 4096;
    short8 af[4], bq[4];
#pragma unroll
    for (int mi = 0; mi < 4; ++mi)
      af[mi] = *reinterpret_cast<const short8*>(&Ab[(rowa + mi * 16) * 32 + kch]);
#pragma unroll
    for (int ni = 0; ni < 4; ++ni)
      bq[ni] = *reinterpret_cast<const short8*>(&Bb[(rowb + ni * 16) * 32 + kch]);
#pragma unroll
    for (int mi = 0; mi < 4; ++mi)
#pragma unroll
      for (int ni = 0; ni < 4; ++ni)
        acc[mi][ni] = __builtin_amdgcn_mfma_f32_16x16x32_bf16(af[mi], bq[ni], acc[mi][ni], 0, 0, 0);
  }

  // epilogue: C/D layout col = lane&15, row = (lane>>4)*4 + reg  [m89-verified]
  const int cc = lane & 15, rr = (lane >> 4) * 4;
  const int rbase = bm * 128 + wm * 64, cbase = bn * 128 + wn * 64;
  if constexpr (EPI == 0) {
    unsigned short* C = (unsigned short*)Cv;
#pragma unroll
    for (int mi = 0; mi < 4; ++mi)
#pragma unroll
      for (int ni = 0; ni < 4; ++ni)
#pragma unroll
        for (int r = 0; r < 4; ++r)
          C[(size_t)(rbase + mi * 16 + rr + r) * ldc + (cbase + ni * 16 + cc)] =
              f2b(acc[mi][ni][r]);
  } else if constexpr (EPI == 1) {
    float* C = (float*)Cv;
#pragma unroll
    for (int mi = 0; mi < 4; ++mi)
#pragma unroll
      for (int ni = 0; ni < 4; ++ni)
#pragma unroll
        for (int r = 0; r < 4; ++r)
          C[(size_t)(rbase + mi * 16 + rr + r) * ldc + (cbase + ni * 16 + cc)] =
              acc[mi][ni][r] * scale;
  } else {
    float* C = (float*)Cv;
#pragma unroll
    for (int mi = 0; mi < 4; ++mi)
#pragma unroll
      for (int ni = 0; ni < 4; ++ni)
#pragma unroll
        for (int r = 0; r < 4; ++r) {
          const size_t idx = (size_t)(rbase + mi * 16 + rr + r) * ldc + (cbase + ni * 16 + cc);
          C[idx] = acc[mi][ni][r] + resid[idx];
        }
  }
}

// ---------------------------------------------------------------------------
// prep unit (same body as R10's prep_kernel, id = unit index in [0,6720))
DEVI void prep_unit(int id, const float* __restrict__ x1, const float* __restrict__ x2,
                    const float* __restrict__ Wq, const float* __restrict__ Wk,
                    const float* __restrict__ Wv, unsigned short* __restrict__ x1fT,
                    unsigned short* __restrict__ x2fT, unsigned short* __restrict__ Wqb,
                    unsigned short* __restrict__ Wkb, unsigned short* __restrict__ Wvb,
                    char* smem) {
  const int tid = threadIdx.x;
  float (*tile)[33] = (float(*)[33])smem;
  if (id < 3072) {
    __syncthreads();  // guard LDS reuse across grid-stride units
    const int c0 = (id % 12) * 64;
    const int ho = (id / 12) % 32;
    const int b = id / 384;
    const int ci = tid >> 5, wo = tid & 31;
#pragma unroll 2
    for (int cc = 0; cc < 8; ++cc) {
      const int c = c0 + cc * 8 + ci;
      const float* base = x1 + ((size_t)(b * 768 + c) * 128 + ho * 4) * 128 + wo * 4;
      float s = 0.f;
#pragma unroll
      for (int i = 0; i < 4; ++i) {
        f32x4 v = *reinterpret_cast<const f32x4*>(base + (size_t)i * 128);
        s += v[0] + v[1] + v[2] + v[3];
      }
      tile[cc * 8 + ci][wo] = s * 0.0625f;
    }
    __syncthreads();
    const int wo2 = tid >> 3, cg = tid & 7;
    uint4 pk;
    pk.x = (unsigned)f2b(tile[cg * 8 + 0][wo2]) | ((unsigned)f2b(tile[cg * 8 + 1][wo2]) << 16);
    pk.y = (unsigned)f2b(tile[cg * 8 + 2][wo2]) | ((unsigned)f2b(tile[cg * 8 + 3][wo2]) << 16);
    pk.z = (unsigned)f2b(tile[cg * 8 + 4][wo2]) | ((unsigned)f2b(tile[cg * 8 + 5][wo2]) << 16);
    pk.w = (unsigned)f2b(tile[cg * 8 + 6][wo2]) | ((unsigned)f2b(tile[cg * 8 + 7][wo2]) << 16);
    *reinterpret_cast<uint4*>(&x1fT[(size_t)(b * 1024 + ho * 32 + wo2) * 768 + c0 + cg * 8]) = pk;
  } else if (id < 6144) {
    __syncthreads();
    id -= 3072;
    const int ct = id % 12;
    const int nt = (id / 12) % 32;
    const int b = id / 384;
    {
      const int nl = tid & 31, cb = tid >> 5;
#pragma unroll
      for (int p = 0; p < 8; ++p) {
        const int cl = p * 8 + cb;
        tile[cl][nl] = x2[(size_t)(b * 768 + ct * 64 + cl) * 1024 + nt * 32 + nl];
      }
    }
    __syncthreads();
    {
      const int c2 = tid & 63, nb = tid >> 6;
#pragma unroll
      for (int p = 0; p < 8; ++p) {
        const int nl = p * 4 + nb;
        x2fT[(size_t)(b * 1024 + nt * 32 + nl) * 768 + ct * 64 + c2] = f2b(tile[c2][nl]);
      }
    }
  } else {
    const int i = (id - 6144) * 256 + tid;
    f32x4 a = reinterpret_cast<const f32x4*>(Wq)[i];
    f32x4 b = reinterpret_cast<const f32x4*>(Wk)[i];
    f32x4 c = reinterpret_cast<const f32x4*>(Wv)[i];
    uint2 oa, ob, oc;
    oa.x = (unsigned)f2b(a[0]) | ((unsigned)f2b(a[1]) << 16);
    oa.y = (unsigned)f2b(a[2]) | ((unsigned)f2b(a[3]) << 16);
    ob.x = (unsigned)f2b(b[0]) | ((unsigned)f2b(b[1]) << 16);
    ob.y = (unsigned)f2b(b[2]) | ((unsigned)f2b(b[3]) << 16);
    oc.x = (unsigned)f2b(c[0]) | ((unsigned)f2b(c[1]) << 16);
    oc.y = (unsigned)f2b(c[2]) | ((unsigned)f2b(c[3]) << 16);
    reinterpret_cast<uint2*>(Wqb)[i] = oa;
    reinterpret_cast<uint2*>(Wkb)[i] = ob;
    reinterpret_cast<uint2*>(Wvb)[i] = oc;
  }
}

// ---------------------------------------------------------------------------
// softmax unit (4 rows per unit, one per wave) — same body as R10
DEVI void softmax_unit(int u, const float* __restrict__ S, unsigned short* __restrict__ P) {
  const int row = u * 4 + (threadIdx.x >> 6);
  const int lane = threadIdx.x & 63;
  const float* r0 = S + (size_t)row * 768;
  const float* r1 = r0 + (size_t)8 * 589824;
  f32x4 v[3];
  float mx = -1e30f;
#pragma unroll
  for (int i = 0; i < 3; ++i) {
    f32x4 a = *reinterpret_cast<const f32x4*>(r0 + (i * 64 + lane) * 4);
    f32x4 b = *reinterpret_cast<const f32x4*>(r1 + (i * 64 + lane) * 4);
    v[i][0] = a[0] + b[0]; v[i][1] = a[1] + b[1];
    v[i][2] = a[2] + b[2]; v[i][3] = a[3] + b[3];
    mx = fmaxf(fmaxf(fmaxf(v[i][0], v[i][1]), fmaxf(v[i][2], v[i][3])), mx);
  }
#pragma unroll
  for (int off = 32; off > 0; off >>= 1) mx = fmaxf(mx, __shfl_xor(mx, off));
  float sum = 0.f;
#pragma unroll
  for (int i = 0; i < 3; ++i)
#pragma unroll
    for (int j = 0; j < 4; ++j) {
      v[i][j] = __expf(v[i][j] - mx);
      sum += v[i][j];
    }
#pragma unroll
  for (int off = 32; off > 0; off >>= 1) sum += __shfl_xor(sum, off);
  const float inv = 1.f / sum;
  unsigned short* p = P + (size_t)row * 768;
#pragma unroll
  for (int i = 0; i < 3; ++i) {
    uint2 o;
    o.x = (unsigned)f2b(v[i][0] * inv) | ((unsigned)f2b(v[i][1] * inv) << 16);
    o.y = (unsigned)f2b(v[i][2] * inv) | ((unsigned)f2b(v[i][3] * inv) << 16);
    *reinterpret_cast<uint2*>(p + (i * 64 + lane) * 4) = o;
  }
}

// ---------------------------------------------------------------------------
// PERSISTENT FUSED PIPELINE: prep | qkv | attn | softmax | out with grid
// barriers. 1024 blocks co-resident (256 CU x 4). Phase bodies == R10.
__global__ __launch_bounds__(256, 4) void fused_kernel(
    const float* __restrict__ x1, const float* __restrict__ x2,
    const float* __restrict__ Wq, const float* __restrict__ Wk,
    const float* __restrict__ Wv, float* __restrict__ out,
    unsigned short* x1fT, unsigned short* x2fT, unsigned short* Wqb,
    unsigned short* Wkb, unsigned short* Wvb, unsigned short* qb,
    unsigned short* kb, unsigned short* vTb, float* attnp,
    unsigned short* attnb, unsigned* bar) {
  __shared__ char smem[32768];
  unsigned short* lds = (unsigned short*)smem;
  const int bid = blockIdx.x;

  // phase 0: prep (6720 units)
  for (int u = bid; u < 6720; u += NBLOCKS)
    prep_unit(u, x1, x2, Wq, Wk, Wv, x1fT, x2fT, Wqb, Wkb, Wvb, smem);
  gbar(bar + 0);

  // phase 1: qkv (1152 tiles)
  for (int u = bid; u < 1152; u += NBLOCKS) {
    if (u < 384) {
      gemm_body<0>(Wkb, x1fT, kb, nullptr, u >> 6, u & 63, 768, 768, 768, 8192, 1.f, lds);
    } else if (u < 768) {
      int t = u - 384;
      gemm_body<0>(Wqb, x2fT, qb, nullptr, t >> 6, t & 63, 768, 768, 768, 8192, 1.f, lds);
    } else {
      int t = u - 768;
      gemm_body<0>(x1fT, Wvb, vTb, nullptr, t / 6, t % 6, 768, 768, 768, 768, 1.f, lds);
    }
  }
  gbar(bar + 16);

  // phase 2: attn partials, split-K=2 (576 tiles; z = kh*8+b)
  for (int u = bid; u < 576; u += NBLOCKS) {
    const int bn = u % 6, bm = (u / 6) % 6, z = u / 36;
    const int b = z & 7, kh = z >> 3;
    gemm_body<1>(qb + b * 1024 + kh * 512, kb + b * 1024 + kh * 512,
                 attnp + (size_t)z * 589824, nullptr, bm, bn, 512, 8192, 8192, 768,
                 1.f / 32.f, lds);
  }
  gbar(bar + 32);

  // phase 3: softmax (1536 units of 4 rows)
  for (int u = bid; u < 1536; u += NBLOCKS) softmax_unit(u, attnp, attnb);
  gbar(bar + 48);

  // phase 4: out (384 tiles)
  for (int u = bid; u < 384; u += NBLOCKS) {
    const int bn = u % 8, bm = (u / 8) % 6, bz = u / 48;
    gemm_body<2>(attnb + (size_t)bz * 589824, vTb + (size_t)bz * 786432,
                 out + (size_t)bz * 786432, x2 + (size_t)bz * 786432, bm, bn,
                 768, 768, 768, 1024, 1.f, lds);
  }
}

// ---------------------------------------------------------------------------
extern "C" void kernel_launch(void* const* d_in, const int* in_sizes, int n_in,
                              void* d_out, int out_size, void* d_ws, size_t ws_size,
                              hipStream_t stream) {
  const float* x1 = (const float*)d_in[0];  // [8][768][128][128]
  const float* x2 = (const float*)d_in[1];  // [8][768][32][32]
  const float* Wq = (const float*)d_in[2];  // [768][768]
  const float* Wk = (const float*)d_in[3];
  const float* Wv = (const float*)d_in[4];
  float* out = (float*)d_out;  // [8][768][32][32]

  char* ws = (char*)d_ws;
  unsigned* bar = (unsigned*)ws;  // 256 B of barrier counters (4 x 64B-spaced)
  size_t off = 256;
  auto alloc = [&](size_t bytes) {
    char* p = ws + off;
    off += (bytes + 255) & ~(size_t)255;
    return p;
  };
  unsigned short* x1fT = (unsigned short*)alloc((size_t)8192 * 768 * 2);  // [b*n][c1]
  unsigned short* x2fT = (unsigned short*)alloc((size_t)8192 * 768 * 2);  // [b*n][c2]
  unsigned short* Wqb = (unsigned short*)alloc((size_t)589824 * 2);
  unsigned short* Wkb = (unsigned short*)alloc((size_t)589824 * 2);
  unsigned short* Wvb = (unsigned short*)alloc((size_t)589824 * 2);
  unsigned short* qb = (unsigned short*)alloc((size_t)768 * 8192 * 2);   // [c2][b*n]
  unsigned short* kb = (unsigned short*)alloc((size_t)768 * 8192 * 2);   // [c1][b*n]
  unsigned short* vTb = (unsigned short*)alloc((size_t)8192 * 768 * 2);  // [b*n][c1]
  float* attnp = (float*)alloc((size_t)2 * 8 * 768 * 768 * 4);           // [kh][b][c2][c1]
  unsigned short* attnb = x2fT;  // overlay: x2fT dead after q-GEMM (barrier-separated)

  hipMemsetAsync(bar, 0, 256, stream);  // zero barrier counters (graph-capturable)
  fused_kernel<<<dim3(NBLOCKS), 256, 0, stream>>>(x1, x2, Wq, Wk, Wv, out, x1fT, x2fT,
                                                  Wqb, Wkb, Wvb, qb, kb, vTb, attnp,
                                                  attnb, bar);
}

// Round 14
// 752.124 us; speedup vs baseline: 1.6233x; 1.6233x over previous
//
#include <hip/hip_runtime.h>
#include <stdint.h>

typedef __attribute__((ext_vector_type(8))) short short8;
typedef __attribute__((ext_vector_type(4))) float f32x4;

#define DEVI __device__ __forceinline__

// float -> bf16 bits, round-to-nearest-even
DEVI unsigned short f2b(float f) {
  union { float f; unsigned u; } v; v.f = f;
  return (unsigned short)((v.u + 0x7fffu + ((v.u >> 16) & 1u)) >> 16);
}

// async global->LDS, 16B per lane; LDS dest must be wave-uniform base + lane*16
#define GLD16(g, s) __builtin_amdgcn_global_load_lds( \
    (const __attribute__((address_space(1))) void*)(g), \
    (__attribute__((address_space(3))) void*)(s), 16, 0, 0)

#define ATO_BLOCKS 512u  // 2/CU guaranteed residency -> cooperative-safe

// Grid barrier, R12-lesson version: RMW only on arrival; poll via agent-scope
// LOAD (coherent point, no cache-line ownership ping-pong). Counter zeroed by
// hipMemsetAsync pre-launch. Device-scope atomicAdd per m20; fences per G16.
DEVI void gbar(unsigned* cnt, unsigned n) {
  __syncthreads();
  if (threadIdx.x == 0) {
    __threadfence();  // release: phase writes visible device-wide
    atomicAdd(cnt, 1u);
    while (__hip_atomic_load(cnt, __ATOMIC_RELAXED, __HIP_MEMORY_SCOPE_AGENT) < n)
      __builtin_amdgcn_s_sleep(16);
    __threadfence();  // acquire
  }
  __syncthreads();
}

// ---------------------------------------------------------------------------
// NT GEMM body (R7-exact, best-measured 633.9us): C[M][N] = A[M][K]*B[N][K]^T,
// 128x128 tile, BK=32, 4 waves, 3-buffer LDS ring, stage-after-barrier,
// counted vmcnt(4), swizzled staging/read. EPI: 0 bf16; 1 f32*scale; 2 f32+resid
template <int EPI>
DEVI void gemm_body(const unsigned short* __restrict__ A,
                    const unsigned short* __restrict__ B, void* __restrict__ Cv,
                    const float* __restrict__ resid, int bm, int bn, int K, int lda,
                    int ldb, int ldc, float scale, unsigned short* lds) {
  const int tid = threadIdx.x;
  const int wave = tid >> 6, lane = tid & 63;
  const int wm = wave >> 1, wn = wave & 1;

  f32x4 acc[4][4] = {};

  const int r0 = wave * 32 + (lane >> 2);
  const int c0 = (((lane & 3) ^ ((lane >> 3) & 3)) * 8);  // swizzled source slot
  const unsigned short* ga = A + (size_t)(bm * 128 + r0) * lda + c0;
  const unsigned short* gb = B + (size_t)(bn * 128 + r0) * ldb + c0;
  const size_t stepA16 = (size_t)16 * lda;
  const size_t stepB16 = (size_t)16 * ldb;
  unsigned short* sbase = lds + wave * 1024 + lane * 8;

  const int rowa = wm * 64 + (lane & 15);
  const int rowb = wn * 64 + (lane & 15);
  const int kch = (((lane >> 4) ^ ((lane >> 1) & 3)) * 8);  // swizzled read slot

  const int nK = K >> 5;

  auto stage = [&](int kt, int buf) {
    const unsigned short* gA = ga + kt * 32;
    const unsigned short* gB = gb + kt * 32;
    unsigned short* dA = sbase + buf * 8192;
    unsigned short* dB = dA + 4096;
    GLD16(gA, dA);
    GLD16(gA + stepA16, dA + 512);
    GLD16(gB, dB);
    GLD16(gB + stepB16, dB + 512);
  };

  stage(0, 0);
  stage(1, 1);  // 8 loads in flight
  int bcur = 0;
  for (int kt = 0; kt < nK; ++kt) {
    if (kt + 1 < nK) {
      asm volatile("s_waitcnt vmcnt(4)" ::: "memory");  // stage(kt) resident
    } else {
      asm volatile("s_waitcnt vmcnt(0)" ::: "memory");
    }
    __builtin_amdgcn_s_barrier();
    asm volatile("" ::: "memory");
    if (kt + 2 < nK) {
      int bpre = bcur + 2; if (bpre >= 3) bpre -= 3;
      stage(kt + 2, bpre);  // overwrites buf (kt-1)%3: consumed by all waves
    }
    const unsigned short* Ab = lds + bcur * 8192;
    const unsigned short* Bb = Ab + 4096;
    short8 af[4], bq[4];
#pragma unroll
    for (int mi = 0; mi < 4; ++mi)
      af[mi] = *reinterpret_cast<const short8*>(&Ab[(rowa + mi * 16) * 32 + kch]);
#pragma unroll
    for (int ni = 0; ni < 4; ++ni)
      bq[ni] = *reinterpret_cast<const short8*>(&Bb[(rowb + ni * 16) * 32 + kch]);
#pragma unroll
    for (int mi = 0; mi < 4; ++mi)
#pragma unroll
      for (int ni = 0; ni < 4; ++ni)
        acc[mi][ni] = __builtin_amdgcn_mfma_f32_16x16x32_bf16(af[mi], bq[ni], acc[mi][ni], 0, 0, 0);
    ++bcur; if (bcur == 3) bcur = 0;
  }

  // epilogue: C/D layout col = lane&15, row = (lane>>4)*4 + reg  [m89-verified]
  const int cc = lane & 15, rr = (lane >> 4) * 4;
  const int rbase = bm * 128 + wm * 64, cbase = bn * 128 + wn * 64;
  if constexpr (EPI == 0) {
    unsigned short* C = (unsigned short*)Cv;
#pragma unroll
    for (int mi = 0; mi < 4; ++mi)
#pragma unroll
      for (int ni = 0; ni < 4; ++ni)
#pragma unroll
        for (int r = 0; r < 4; ++r)
          C[(size_t)(rbase + mi * 16 + rr + r) * ldc + (cbase + ni * 16 + cc)] =
              f2b(acc[mi][ni][r]);
  } else if constexpr (EPI == 1) {
    float* C = (float*)Cv;
#pragma unroll
    for (int mi = 0; mi < 4; ++mi)
#pragma unroll
      for (int ni = 0; ni < 4; ++ni)
#pragma unroll
        for (int r = 0; r < 4; ++r)
          C[(size_t)(rbase + mi * 16 + rr + r) * ldc + (cbase + ni * 16 + cc)] =
              acc[mi][ni][r] * scale;
  } else {
    float* C = (float*)Cv;
#pragma unroll
    for (int mi = 0; mi < 4; ++mi)
#pragma unroll
      for (int ni = 0; ni < 4; ++ni)
#pragma unroll
        for (int r = 0; r < 4; ++r) {
          const size_t idx = (size_t)(rbase + mi * 16 + rr + r) * ldc + (cbase + ni * 16 + cc);
          C[idx] = acc[mi][ni][r] + resid[idx];
        }
  }
}

// ---------------------------------------------------------------------------
// PREP (R7-exact): pool(x1)->x1fT bf16 | transpose(x2)->x2fT bf16 | W->bf16
__global__ __launch_bounds__(256) void prep_kernel(
    const float* __restrict__ x1, const float* __restrict__ x2,
    const float* __restrict__ Wq, const float* __restrict__ Wk,
    const float* __restrict__ Wv, unsigned short* __restrict__ x1fT,
    unsigned short* __restrict__ x2fT, unsigned short* __restrict__ Wqb,
    unsigned short* __restrict__ Wkb, unsigned short* __restrict__ Wvb) {
  const int tid = threadIdx.x;
  __shared__ float tile[64][33];
  int id = blockIdx.x;
  if (id < 3072) {
    const int c0 = (id % 12) * 64;
    const int ho = (id / 12) % 32;
    const int b = id / 384;
    const int ci = tid >> 5, wo = tid & 31;
#pragma unroll 2
    for (int cc = 0; cc < 8; ++cc) {
      const int c = c0 + cc * 8 + ci;
      const float* base = x1 + ((size_t)(b * 768 + c) * 128 + ho * 4) * 128 + wo * 4;
      float s = 0.f;
#pragma unroll
      for (int i = 0; i < 4; ++i) {
        f32x4 v = *reinterpret_cast<const f32x4*>(base + (size_t)i * 128);
        s += v[0] + v[1] + v[2] + v[3];
      }
      tile[cc * 8 + ci][wo] = s * 0.0625f;
    }
    __syncthreads();
    const int wo2 = tid >> 3, cg = tid & 7;
    uint4 pk;
    pk.x = (unsigned)f2b(tile[cg * 8 + 0][wo2]) | ((unsigned)f2b(tile[cg * 8 + 1][wo2]) << 16);
    pk.y = (unsigned)f2b(tile[cg * 8 + 2][wo2]) | ((unsigned)f2b(tile[cg * 8 + 3][wo2]) << 16);
    pk.z = (unsigned)f2b(tile[cg * 8 + 4][wo2]) | ((unsigned)f2b(tile[cg * 8 + 5][wo2]) << 16);
    pk.w = (unsigned)f2b(tile[cg * 8 + 6][wo2]) | ((unsigned)f2b(tile[cg * 8 + 7][wo2]) << 16);
    *reinterpret_cast<uint4*>(&x1fT[(size_t)(b * 1024 + ho * 32 + wo2) * 768 + c0 + cg * 8]) = pk;
  } else if (id < 6144) {
    id -= 3072;
    const int ct = id % 12;
    const int nt = (id / 12) % 32;
    const int b = id / 384;
    {
      const int nl = tid & 31, cb = tid >> 5;
#pragma unroll
      for (int p = 0; p < 8; ++p) {
        const int cl = p * 8 + cb;
        tile[cl][nl] = x2[(size_t)(b * 768 + ct * 64 + cl) * 1024 + nt * 32 + nl];
      }
    }
    __syncthreads();
    {
      const int c2 = tid & 63, nb = tid >> 6;
#pragma unroll
      for (int p = 0; p < 8; ++p) {
        const int nl = p * 4 + nb;
        x2fT[(size_t)(b * 1024 + nt * 32 + nl) * 768 + ct * 64 + c2] = f2b(tile[c2][nl]);
      }
    }
  } else {
    const int i = (id - 6144) * 256 + tid;
    f32x4 a = reinterpret_cast<const f32x4*>(Wq)[i];
    f32x4 b = reinterpret_cast<const f32x4*>(Wk)[i];
    f32x4 c = reinterpret_cast<const f32x4*>(Wv)[i];
    uint2 oa, ob, oc;
    oa.x = (unsigned)f2b(a[0]) | ((unsigned)f2b(a[1]) << 16);
    oa.y = (unsigned)f2b(a[2]) | ((unsigned)f2b(a[3]) << 16);
    ob.x = (unsigned)f2b(b[0]) | ((unsigned)f2b(b[1]) << 16);
    ob.y = (unsigned)f2b(b[2]) | ((unsigned)f2b(b[3]) << 16);
    oc.x = (unsigned)f2b(c[0]) | ((unsigned)f2b(c[1]) << 16);
    oc.y = (unsigned)f2b(c[2]) | ((unsigned)f2b(c[3]) << 16);
    reinterpret_cast<uint2*>(Wqb)[i] = oa;
    reinterpret_cast<uint2*>(Wkb)[i] = ob;
    reinterpret_cast<uint2*>(Wvb)[i] = oc;
  }
}

// ---------------------------------------------------------------------------
// QKV (R7-exact, 1152 blocks, 3/CU)
__global__ __launch_bounds__(256, 3) void qkv_kernel(
    const unsigned short* __restrict__ Wkb, const unsigned short* __restrict__ Wqb,
    const unsigned short* __restrict__ Wvb, const unsigned short* __restrict__ x1fT,
    const unsigned short* __restrict__ x2fT, unsigned short* __restrict__ kb,
    unsigned short* __restrict__ qb, unsigned short* __restrict__ vTb) {
  __shared__ unsigned short lds[3 * 8192];
  int id = blockIdx.x;
  if (id < 384) {
    gemm_body<0>(Wkb, x1fT, kb, nullptr, id >> 6, id & 63, 768, 768, 768, 8192, 1.f, lds);
  } else if (id < 768) {
    id -= 384;
    gemm_body<0>(Wqb, x2fT, qb, nullptr, id >> 6, id & 63, 768, 768, 768, 8192, 1.f, lds);
  } else {
    id -= 768;
    gemm_body<0>(x1fT, Wvb, vTb, nullptr, id / 6, id % 6, 768, 768, 768, 768, 1.f, lds);
  }
}

// ---------------------------------------------------------------------------
// softmax unit (R7 body as device fn): 4 rows per unit, one per wave
DEVI void softmax_unit(int u, const float* __restrict__ S, unsigned short* __restrict__ P) {
  const int row = u * 4 + (threadIdx.x >> 6);
  const int lane = threadIdx.x & 63;
  const float* r0 = S + (size_t)row * 768;
  const float* r1 = r0 + (size_t)8 * 589824;  // second K-half partial
  f32x4 v[3];
  float mx = -1e30f;
#pragma unroll
  for (int i = 0; i < 3; ++i) {
    f32x4 a = *reinterpret_cast<const f32x4*>(r0 + (i * 64 + lane) * 4);
    f32x4 b = *reinterpret_cast<const f32x4*>(r1 + (i * 64 + lane) * 4);
    v[i][0] = a[0] + b[0]; v[i][1] = a[1] + b[1];
    v[i][2] = a[2] + b[2]; v[i][3] = a[3] + b[3];
    mx = fmaxf(fmaxf(fmaxf(v[i][0], v[i][1]), fmaxf(v[i][2], v[i][3])), mx);
  }
#pragma unroll
  for (int off = 32; off > 0; off >>= 1) mx = fmaxf(mx, __shfl_xor(mx, off));
  float sum = 0.f;
#pragma unroll
  for (int i = 0; i < 3; ++i)
#pragma unroll
    for (int j = 0; j < 4; ++j) {
      v[i][j] = __expf(v[i][j] - mx);
      sum += v[i][j];
    }
#pragma unroll
  for (int off = 32; off > 0; off >>= 1) sum += __shfl_xor(sum, off);
  const float inv = 1.f / sum;
  unsigned short* p = P + (size_t)row * 768;
#pragma unroll
  for (int i = 0; i < 3; ++i) {
    uint2 o;
    o.x = (unsigned)f2b(v[i][0] * inv) | ((unsigned)f2b(v[i][1] * inv) << 16);
    o.y = (unsigned)f2b(v[i][2] * inv) | ((unsigned)f2b(v[i][3] * inv) << 16);
    *reinterpret_cast<uint2*>(p + (i * 64 + lane) * 4) = o;
  }
}

// ---------------------------------------------------------------------------
// ATO: attn(split-K=2) | softmax | out in ONE cooperative dispatch.
// 512 blocks: guaranteed co-resident even at 2 blocks/CU worst case (512=2x256).
// Phase bodies identical to R7/R12-validated code. __syncthreads between
// grid-stride gemm calls guards the LDS ring across tiles (WAR).
__global__ __launch_bounds__(256, 3) void ato_kernel(
    const unsigned short* __restrict__ qb, const unsigned short* __restrict__ kb,
    float* __restrict__ attnp, unsigned short* __restrict__ attnb,
    const unsigned short* __restrict__ vTb, float* __restrict__ out,
    const float* __restrict__ x2, unsigned* bar) {
  __shared__ unsigned short lds[3 * 8192];
  const int bid = blockIdx.x;

  // phase A: attn partials (576 tiles; z = kh*8+b)
  for (unsigned u = bid; u < 576; u += ATO_BLOCKS) {
    __syncthreads();  // ring WAR guard between consecutive tiles
    const int bn = u % 6, bm = (u / 6) % 6, z = u / 36;
    const int b = z & 7, kh = z >> 3;
    gemm_body<1>(qb + b * 1024 + kh * 512, kb + b * 1024 + kh * 512,
                 attnp + (size_t)z * 589824, nullptr, bm, bn, 512, 8192, 8192, 768,
                 1.f / 32.f, lds);
  }
  gbar(bar + 0, ATO_BLOCKS);

  // phase B: softmax (1536 units of 4 rows; exactly 3 per block)
  for (unsigned u = bid; u < 1536; u += ATO_BLOCKS) softmax_unit(u, attnp, attnb);
  gbar(bar + 16, ATO_BLOCKS);

  // phase C: out (384 tiles)
  for (unsigned u = bid; u < 384; u += ATO_BLOCKS) {
    const int bn = u % 8, bm = (u / 8) % 6, bz = u / 48;
    gemm_body<2>(attnb + (size_t)bz * 589824, vTb + (size_t)bz * 786432,
                 out + (size_t)bz * 786432, x2 + (size_t)bz * 786432, bm, bn,
                 768, 768, 768, 1024, 1.f, lds);
  }
}

// ---------------------------------------------------------------------------
extern "C" void kernel_launch(void* const* d_in, const int* in_sizes, int n_in,
                              void* d_out, int out_size, void* d_ws, size_t ws_size,
                              hipStream_t stream) {
  const float* x1 = (const float*)d_in[0];  // [8][768][128][128]
  const float* x2 = (const float*)d_in[1];  // [8][768][32][32]
  const float* Wq = (const float*)d_in[2];  // [768][768]
  const float* Wk = (const float*)d_in[3];
  const float* Wv = (const float*)d_in[4];
  float* out = (float*)d_out;  // [8][768][32][32]

  char* ws = (char*)d_ws;
  unsigned* bar = (unsigned*)ws;  // 2 counters, 64B-spaced, in first 256 B
  size_t off = 256;
  auto alloc = [&](size_t bytes) {
    char* p = ws + off;
    off += (bytes + 255) & ~(size_t)255;
    return p;
  };
  unsigned short* x1fT = (unsigned short*)alloc((size_t)8192 * 768 * 2);  // [b*n][c1]
  unsigned short* x2fT = (unsigned short*)alloc((size_t)8192 * 768 * 2);  // [b*n][c2]
  unsigned short* Wqb = (unsigned short*)alloc((size_t)589824 * 2);
  unsigned short* Wkb = (unsigned short*)alloc((size_t)589824 * 2);
  unsigned short* Wvb = (unsigned short*)alloc((size_t)589824 * 2);
  unsigned short* qb = (unsigned short*)alloc((size_t)768 * 8192 * 2);   // [c2][b*n]
  unsigned short* kb = (unsigned short*)alloc((size_t)768 * 8192 * 2);   // [c1][b*n]
  unsigned short* vTb = (unsigned short*)alloc((size_t)8192 * 768 * 2);  // [b*n][c1]
  float* attnp = (float*)alloc((size_t)2 * 8 * 768 * 768 * 4);           // [kh][b][c2][c1]
  unsigned short* attnb = x2fT;  // overlay: x2fT dead after q-GEMM

  hipMemsetAsync(bar, 0, 256, stream);  // zero barrier counters (graph-capturable)
  // 1. prep
  prep_kernel<<<dim3(6720), 256, 0, stream>>>(x1, x2, Wq, Wk, Wv, x1fT, x2fT, Wqb, Wkb, Wvb);
  // 2. q/k/vT GEMMs (1152 blocks, 3/CU)
  qkv_kernel<<<dim3(1152), 256, 0, stream>>>(Wkb, Wqb, Wvb, x1fT, x2fT, kb, qb, vTb);
  // 3. attn + softmax + out, cooperative (512 blocks, 2 internal barriers)
  ato_kernel<<<dim3(ATO_BLOCKS), 256, 0, stream>>>(qb, kb, attnp, attnb, vTb, out, x2, bar);
}